// Round 4
// baseline (110.021 us; speedup 1.0000x reference)
//
#include <hip/hip_runtime.h>

// Chamfer loss: pred (2048,8,3) vs gt (2048,8,3) fp32. N=16384 pts/side.
// out = mean(min_m d) + mean(min_n d); 8-corner group-mean == global mean.
//
// R4:
//  - revert v2f packing (R3 showed fp32 is execution-bound, not issue-bound:
//    VALUBusy 105->64% with identical dur. pk_fma retires same lanes/cyc).
//  - y processed in pairs: fmaxf(mx, fmaxf(t0,t1)) -> v_max3_f32 peephole,
//    3.5 VALU slots/pair instead of 4.
//  - NO ATOMICS: k1 writes per-(x, y-seg) partial d2 with plain stores to ws
//    (2*64*16384 floats = 8 MB); k2 min-combines 64 segs + sqrt + block-sum
//    -> 128 partial sums; k3 (1 block) finishes. Kills the ~50 us of
//    init/atomicMin/atomicAdd(out) overhead (16.8 MB atomic write-through,
//    256 serialized same-address adds).
//  - fallback to the R3 atomic path if ws_size < 8 MB (host branch on
//    ws_size is deterministic -> graph-capture safe).

#define NPTS   16384
#define RPT    8              // x-points per thread
#define BLOCK  256
#define XPB    (RPT * BLOCK)  // 2048 x-points per block
#define NXB    (NPTS / XPB)   // 8 x-blocks
#define NSEG   64             // y segments -> 2*8*64 = 1024 blocks (4/CU)
#define YSEG   (NPTS / NSEG)  // 256 y-points per segment (one LDS chunk)
#define NPART  (2 * NSEG * NPTS)          // partial-d2 floats in ws
#define K2B    128                        // k2 blocks
#define WS_NEED ((NPART + K2B) * 4)

// ---------------- main path (no atomics) ----------------

__global__ __launch_bounds__(BLOCK, 4) void chamfer_partial(
        const float* __restrict__ pred, const float* __restrict__ gt,
        float* __restrict__ part) {
    const int xb  = blockIdx.x;
    const int ys  = blockIdx.y;
    const int dir = blockIdx.z;
    const float* __restrict__ X = dir ? gt : pred;
    const float* __restrict__ Y = dir ? pred : gt;
    const int tid = threadIdx.x;

    __shared__ float4 sh[YSEG];  // (yx, yy, yz, -|y|^2/2)
    {
        int yi = ys * YSEG + tid;
        float a = Y[3 * yi + 0], b = Y[3 * yi + 1], c = Y[3 * yi + 2];
        sh[tid] = make_float4(a, b, c, -0.5f * (a * a + b * b + c * c));
    }

    float xx[RPT], xy[RPT], xz[RPT], x2[RPT], mx[RPT];
    const int xbase = xb * XPB;
#pragma unroll
    for (int r = 0; r < RPT; ++r) {
        int xi = xbase + r * BLOCK + tid;
        xx[r] = X[3 * xi + 0];
        xy[r] = X[3 * xi + 1];
        xz[r] = X[3 * xi + 2];
        x2[r] = xx[r] * xx[r] + xy[r] * xy[r] + xz[r] * xz[r];
        mx[r] = -3.0e38f;
    }

    __syncthreads();

#pragma unroll 2
    for (int j = 0; j < YSEG; j += 2) {
        float4 y0 = sh[j];      // uniform address -> broadcast, conflict-free
        float4 y1 = sh[j + 1];
#pragma unroll
        for (int r = 0; r < RPT; ++r) {
            float t0 = fmaf(xz[r], y0.z, y0.w);
            t0 = fmaf(xy[r], y0.y, t0);
            t0 = fmaf(xx[r], y0.x, t0);
            float t1 = fmaf(xz[r], y1.z, y1.w);
            t1 = fmaf(xy[r], y1.y, t1);
            t1 = fmaf(xx[r], y1.x, t1);
            mx[r] = fmaxf(mx[r], fmaxf(t0, t1));  // -> v_max3_f32
        }
    }

    float* __restrict__ dst = part + (dir * NSEG + ys) * NPTS;
#pragma unroll
    for (int r = 0; r < RPT; ++r) {
        int xi = xbase + r * BLOCK + tid;
        dst[xi] = fmaf(-2.0f, mx[r], x2[r]);  // partial min d2 (clamp later)
    }
}

__global__ __launch_bounds__(256) void chamfer_combine(
        const float* __restrict__ part, float* __restrict__ sums) {
    const int gid = blockIdx.x * 256 + threadIdx.x;  // 128 blocks x 256
    const int dir = gid >> 14;
    const int x   = gid & (NPTS - 1);
    float m = 3.0e38f;
#pragma unroll 8
    for (int s = 0; s < NSEG; ++s)
        m = fminf(m, part[(dir * NSEG + s) * NPTS + x]);
    float v = sqrtf(fmaxf(m, 0.0f));

#pragma unroll
    for (int off = 32; off > 0; off >>= 1)
        v += __shfl_down(v, off, 64);

    __shared__ float lsum[4];
    if ((threadIdx.x & 63) == 0) lsum[threadIdx.x >> 6] = v;
    __syncthreads();
    if (threadIdx.x == 0)
        sums[blockIdx.x] = lsum[0] + lsum[1] + lsum[2] + lsum[3];
}

__global__ __launch_bounds__(128) void chamfer_final(
        const float* __restrict__ sums, float* __restrict__ out) {
    float v = sums[threadIdx.x];
#pragma unroll
    for (int off = 32; off > 0; off >>= 1)
        v += __shfl_down(v, off, 64);
    __shared__ float w[2];
    if ((threadIdx.x & 63) == 0) w[threadIdx.x >> 6] = v;
    __syncthreads();
    if (threadIdx.x == 0) out[0] = (w[0] + w[1]) * (1.0f / (float)NPTS);
}

// ---------------- fallback path (small ws): R3 atomic version ----------------

__global__ __launch_bounds__(256) void init_mins(unsigned int* mins, float* out) {
    int i = blockIdx.x * blockDim.x + threadIdx.x;
    if (i < 2 * NPTS) mins[i] = 0x7F800000u;
    if (i == 0) out[0] = 0.0f;
}

__global__ __launch_bounds__(BLOCK, 4) void chamfer_min_atomic(
        const float* __restrict__ pred, const float* __restrict__ gt,
        unsigned int* __restrict__ mins) {
    const int xb  = blockIdx.x;
    const int ys  = blockIdx.y;
    const int dir = blockIdx.z;
    const float* __restrict__ X = dir ? gt : pred;
    const float* __restrict__ Y = dir ? pred : gt;
    unsigned int* __restrict__ outm = mins + dir * NPTS;
    const int tid = threadIdx.x;

    __shared__ float4 sh[YSEG];
    {
        int yi = ys * YSEG + tid;
        float a = Y[3 * yi + 0], b = Y[3 * yi + 1], c = Y[3 * yi + 2];
        sh[tid] = make_float4(a, b, c, -0.5f * (a * a + b * b + c * c));
    }
    float xx[RPT], xy[RPT], xz[RPT], x2[RPT], mx[RPT];
    const int xbase = xb * XPB;
#pragma unroll
    for (int r = 0; r < RPT; ++r) {
        int xi = xbase + r * BLOCK + tid;
        xx[r] = X[3 * xi + 0];
        xy[r] = X[3 * xi + 1];
        xz[r] = X[3 * xi + 2];
        x2[r] = xx[r] * xx[r] + xy[r] * xy[r] + xz[r] * xz[r];
        mx[r] = -3.0e38f;
    }
    __syncthreads();
#pragma unroll 2
    for (int j = 0; j < YSEG; j += 2) {
        float4 y0 = sh[j], y1 = sh[j + 1];
#pragma unroll
        for (int r = 0; r < RPT; ++r) {
            float t0 = fmaf(xz[r], y0.z, y0.w);
            t0 = fmaf(xy[r], y0.y, t0);
            t0 = fmaf(xx[r], y0.x, t0);
            float t1 = fmaf(xz[r], y1.z, y1.w);
            t1 = fmaf(xy[r], y1.y, t1);
            t1 = fmaf(xx[r], y1.x, t1);
            mx[r] = fmaxf(mx[r], fmaxf(t0, t1));
        }
    }
#pragma unroll
    for (int r = 0; r < RPT; ++r) {
        int xi = xbase + r * BLOCK + tid;
        float d2 = fmaxf(fmaf(-2.0f, mx[r], x2[r]), 0.0f);
        atomicMin(&outm[xi], __float_as_uint(d2));
    }
}

__global__ __launch_bounds__(256) void chamfer_reduce_atomic(
        const unsigned int* __restrict__ mins, float* __restrict__ out) {
    const int gid = blockIdx.x * 256 + threadIdx.x;
    float s = 0.0f;
#pragma unroll
    for (int i = 0; i < 2; ++i)
        s += sqrtf(__uint_as_float(mins[gid + i * 64 * 256]));
#pragma unroll
    for (int off = 32; off > 0; off >>= 1)
        s += __shfl_down(s, off, 64);
    if ((threadIdx.x & 63) == 0)
        atomicAdd(out, s * (1.0f / (float)NPTS));
}

extern "C" void kernel_launch(void* const* d_in, const int* in_sizes, int n_in,
                              void* d_out, int out_size, void* d_ws, size_t ws_size,
                              hipStream_t stream) {
    const float* pred = (const float*)d_in[0];
    const float* gt   = (const float*)d_in[1];
    float* out        = (float*)d_out;

    if (ws_size >= (size_t)WS_NEED) {
        float* part = (float*)d_ws;
        float* sums = part + NPART;
        hipLaunchKernelGGL(chamfer_partial, dim3(NXB, NSEG, 2), dim3(BLOCK), 0,
                           stream, pred, gt, part);
        hipLaunchKernelGGL(chamfer_combine, dim3(K2B), dim3(256), 0, stream,
                           part, sums);
        hipLaunchKernelGGL(chamfer_final, dim3(1), dim3(128), 0, stream,
                           sums, out);
    } else {
        unsigned int* mins = (unsigned int*)d_ws;  // 128 KB
        hipLaunchKernelGGL(init_mins, dim3((2 * NPTS + 255) / 256), dim3(256), 0,
                           stream, mins, out);
        hipLaunchKernelGGL(chamfer_min_atomic, dim3(NXB, NSEG, 2), dim3(BLOCK), 0,
                           stream, pred, gt, mins);
        hipLaunchKernelGGL(chamfer_reduce_atomic, dim3(64), dim3(256), 0, stream,
                           mins, out);
    }
}